// Round 3
// baseline (7554.580 us; speedup 1.0000x reference)
//
#include <hip/hip_runtime.h>
#include <hip/hip_bf16.h>

typedef __attribute__((ext_vector_type(8))) short bh8;
typedef __attribute__((ext_vector_type(4))) float fx4;
typedef __attribute__((ext_vector_type(4))) int ix4;
typedef __attribute__((ext_vector_type(2))) unsigned int ux2;

#define MFMA_BF16(a,b,c) __builtin_amdgcn_mfma_f32_16x16x32_bf16((a),(b),(c),0,0,0)

__device__ __forceinline__ unsigned short f2bf(float f){
  union { float f; unsigned u; } x; x.f = f;
  return (unsigned short)((x.u + 0x7fffu + ((x.u >> 16) & 1u)) >> 16);
}

__device__ __forceinline__ void gl_lds16(const void* g, void* l){
  typedef const void __attribute__((address_space(1)))* gp_t;
  typedef void __attribute__((address_space(3)))* lp_t;
  __builtin_amdgcn_global_load_lds((gp_t)g, (lp_t)l, 16, 0, 0);
}

// ---------------- f32 -> bf16 (RNE), 4 elems/thread ----------------
__global__ __launch_bounds__(256) void cvt_kernel(const float* __restrict__ in,
                                                  unsigned short* __restrict__ out, int n){
  int i = (blockIdx.x * 256 + threadIdx.x) * 4;
  if (i >= n) return;
  float4 v = *reinterpret_cast<const float4*>(in + i);
  ushort4 o;
  o.x = f2bf(v.x); o.y = f2bf(v.y); o.z = f2bf(v.z); o.w = f2bf(v.w);
  *reinterpret_cast<ushort4*>(out + i) = o;
}

// ---------------- NT GEMM: C[M][N] = A[M][K] * B[N][K]^T (m97 structure) ----------------
__global__ __launch_bounds__(256) void gemm_nt(const unsigned short* __restrict__ A,
                                               const unsigned short* __restrict__ B,
                                               void* __restrict__ Cout,
                                               int M, int N, int K, int out_f32){
  __shared__ __attribute__((aligned(16))) unsigned short As[128*32];
  __shared__ __attribute__((aligned(16))) unsigned short Bs[128*32];
  const int tid = threadIdx.x, lane = tid & 63, w = tid >> 6;
  const int row0 = blockIdx.x * 128, col0 = blockIdx.y * 128;
  const int wr = w >> 1, wc = w & 1;
  fx4 acc[4][4];
#pragma unroll
  for (int m=0;m<4;m++)
#pragma unroll
    for (int n=0;n<4;n++) acc[m][n] = (fx4){0.f,0.f,0.f,0.f};

  const int ldr = lane & 15;
  const int kb  = (lane >> 4) * 16;

  for (int k0 = 0; k0 < K; k0 += 32){
    __syncthreads();
#pragma unroll
    for (int i=0;i<2;i++){
      int chunk = w*2 + i;
      int r  = chunk*16 + (lane >> 2);
      int cb = (lane & 3) * 16;
      gl_lds16((const char*)A + ((size_t)(row0 + r)*K + k0)*2 + cb, (char*)As + chunk*1024);
      gl_lds16((const char*)B + ((size_t)(col0 + r)*K + k0)*2 + cb, (char*)Bs + chunk*1024);
    }
    __syncthreads();
    bh8 af[4], bf[4];
#pragma unroll
    for (int m=0;m<4;m++)
      af[m] = *reinterpret_cast<const bh8*>((const char*)As + (wr*64 + m*16 + ldr)*64 + kb);
#pragma unroll
    for (int n=0;n<4;n++)
      bf[n] = *reinterpret_cast<const bh8*>((const char*)Bs + (wc*64 + n*16 + ldr)*64 + kb);
#pragma unroll
    for (int m=0;m<4;m++)
#pragma unroll
      for (int n=0;n<4;n++)
        acc[m][n] = MFMA_BF16(af[m], bf[n], acc[m][n]);
  }
  const int er = (lane >> 4) * 4;
  const int ec = lane & 15;
  if (out_f32){
    float* C = (float*)Cout;
#pragma unroll
    for (int m=0;m<4;m++)
#pragma unroll
      for (int n=0;n<4;n++)
#pragma unroll
        for (int j=0;j<4;j++)
          C[(size_t)(row0 + wr*64 + m*16 + er + j)*N + (col0 + wc*64 + n*16 + ec)] = acc[m][n][j];
  } else {
    unsigned short* C = (unsigned short*)Cout;
#pragma unroll
    for (int m=0;m<4;m++)
#pragma unroll
      for (int n=0;n<4;n++)
#pragma unroll
        for (int j=0;j<4;j++)
          C[(size_t)(row0 + wr*64 + m*16 + er + j)*N + (col0 + wc*64 + n*16 + ec)] = f2bf(acc[m][n][j]);
  }
}

// ---------------- causal GQA flash attention, swapped-QK in-register softmax ----------------
// 4 waves/block; wave w owns q rows {bq*128+w*16+l15} (qc=0) and {+64} (qc=1); KVBLK=64.
// S^T = mfma(K, Q): lane holds 16 P values for q=lane&15 -> in-lane softmax (2 shfl per reduce).
// K/Vt/Ps all XOR-swizzled (byte ^= (row&7)<<4) to kill bank conflicts.
__global__ __launch_bounds__(256,2) void attn_kernel(const unsigned short* __restrict__ Q,
                                                     const unsigned short* __restrict__ Km,
                                                     const unsigned short* __restrict__ Vm,
                                                     unsigned short* __restrict__ O){
  __shared__ __attribute__((aligned(16))) unsigned short Ks[64*128];   // [kv][d], 256B rows, swz
  __shared__ __attribute__((aligned(16))) unsigned short Vt[128*64];   // [d][kv], 128B rows, swz
  __shared__ __attribute__((aligned(16))) unsigned short Ps[4][32*64]; // per-wave P [q][kv], swz
  const int tid = threadIdx.x, lane = tid & 63, w = tid >> 6;
  const int g = lane >> 4, l15 = lane & 15;
  const int bq = (int)gridDim.x - 1 - (int)blockIdx.x;  // heavy blocks first
  const int head = blockIdx.y;
  const int b = head >> 5, h = head & 31, kvh = h >> 2;
  const int q0 = bq*128 + w*16;        // qc=0 base
  const int q1 = q0 + 64;              // qc=1 base
  const size_t tokbase = (size_t)b * 2048;
  const float C2 = 0.12751741104447086f;  // (1/sqrt(128)) * log2(e)

  bh8 qf0[4], qf1[4];
  {
    const char* qp0 = (const char*)Q + ((tokbase + q0 + l15)*4096 + h*128)*2;
    const char* qp1 = (const char*)Q + ((tokbase + q1 + l15)*4096 + h*128)*2;
#pragma unroll
    for (int kk=0;kk<4;kk++){
      qf0[kk] = *reinterpret_cast<const bh8*>(qp0 + kk*64 + g*16);
      qf1[kk] = *reinterpret_cast<const bh8*>(qp1 + kk*64 + g*16);
    }
  }
  float mrow0 = -1e38f, mrow1 = -1e38f, lrow0 = 0.f, lrow1 = 0.f;
  fx4 acc0[8], acc1[8];
#pragma unroll
  for (int f=0;f<8;f++){ acc0[f] = (fx4){0,0,0,0}; acc1[f] = (fx4){0,0,0,0}; }

  const int ntile = 2*bq + 2;
  for (int kt=0; kt<ntile; ++kt){
    const int kv0 = kt*64;
    __syncthreads();
    { // stage K: 64 rows x 256B, 4 x 16B per thread, swizzled
#pragma unroll
      for (int i=0;i<4;i++){
        int idx = i*256 + tid;
        int r = idx >> 4, cb = (idx & 15)*16;
        ix4 kvv = *reinterpret_cast<const ix4*>((const char*)Km + ((tokbase + kv0 + r)*1024 + kvh*128)*2 + cb);
        *reinterpret_cast<ix4*>((char*)Ks + r*256 + (cb ^ ((r&7)<<4))) = kvv;
      }
    }
    { // stage V^T: thread owns d=tid&127, kv-half kh (32 kv); swizzled 128B rows
      int d = tid & 127, kh = tid >> 7;
      const unsigned short* vsrc = Vm + (tokbase + kv0 + kh*32)*1024 + kvh*128 + d;
      unsigned int pk[16];
#pragma unroll
      for (int e=0;e<16;e++){
        unsigned int lo = vsrc[(size_t)(2*e)*1024];
        unsigned int hi = vsrc[(size_t)(2*e+1)*1024];
        pk[e] = lo | (hi << 16);
      }
#pragma unroll
      for (int c=0;c<4;c++){
        ix4 vv; vv[0]=(int)pk[4*c]; vv[1]=(int)pk[4*c+1]; vv[2]=(int)pk[4*c+2]; vv[3]=(int)pk[4*c+3];
        *reinterpret_cast<ix4*>((char*)Vt + d*128 + ((kh*64 + c*16) ^ ((d&7)<<4))) = vv;
      }
    }
    __syncthreads();
    const bool c1 = (kv0 <= q1 + 15);   // wave-uniform
    const bool c0 = (kv0 <= q0 + 15);
    if (c1){
      fx4 s0[4], s1[4];
#pragma unroll
      for (int m=0;m<4;m++){ s0[m] = (fx4){0,0,0,0}; s1[m] = (fx4){0,0,0,0}; }
#pragma unroll
      for (int m=0;m<4;m++){
        bh8 kf[4];
        const int kr = m*16 + l15;
#pragma unroll
        for (int kk=0;kk<4;kk++)
          kf[kk] = *reinterpret_cast<const bh8*>((const char*)Ks + kr*256 + ((kk*64 + g*16) ^ ((kr&7)<<4)));
        if (c0){
#pragma unroll
          for (int kk=0;kk<4;kk++) s0[m] = MFMA_BF16(kf[kk], qf0[kk], s0[m]);
        }
#pragma unroll
        for (int kk=0;kk<4;kk++) s1[m] = MFMA_BF16(kf[kk], qf1[kk], s1[m]);
      }
      // ---- softmax qc=0 ----
      if (c0){
        const int lim = q0 + l15 - kv0 - g*4;
#pragma unroll
        for (int m=0;m<4;m++)
#pragma unroll
          for (int j=0;j<4;j++)
            s0[m][j] = (m*16 + j > lim) ? -1e30f : s0[m][j]*C2;
        float a0 = fmaxf(fmaxf(s0[0][0],s0[0][1]), fmaxf(s0[0][2],s0[0][3]));
        float a1 = fmaxf(fmaxf(s0[1][0],s0[1][1]), fmaxf(s0[1][2],s0[1][3]));
        float a2 = fmaxf(fmaxf(s0[2][0],s0[2][1]), fmaxf(s0[2][2],s0[2][3]));
        float a3 = fmaxf(fmaxf(s0[3][0],s0[3][1]), fmaxf(s0[3][2],s0[3][3]));
        float mx = fmaxf(fmaxf(a0,a1), fmaxf(a2,a3));
        mx = fmaxf(mx, __shfl_xor(mx, 16));
        mx = fmaxf(mx, __shfl_xor(mx, 32));
        if (__any(mx > mrow0 + 8.f)){
          float mnew = fmaxf(mrow0, mx);
          float sc = exp2f(mrow0 - mnew);
          mrow0 = mnew;
          lrow0 *= sc;
          float sct[4];
#pragma unroll
          for (int j=0;j<4;j++) sct[j] = __shfl(sc, g*4 + j);
#pragma unroll
          for (int f=0;f<8;f++)
#pragma unroll
            for (int j=0;j<4;j++) acc0[f][j] *= sct[j];
        }
        float rs = 0.f;
        ux2 pw[4];
#pragma unroll
        for (int m=0;m<4;m++){
          float p0 = exp2f(s0[m][0]-mrow0), p1 = exp2f(s0[m][1]-mrow0);
          float p2 = exp2f(s0[m][2]-mrow0), p3 = exp2f(s0[m][3]-mrow0);
          rs += (p0+p1)+(p2+p3);
          ux2 t; t[0] = (unsigned)f2bf(p0) | ((unsigned)f2bf(p1)<<16);
          t[1] = (unsigned)f2bf(p2) | ((unsigned)f2bf(p3)<<16);
          pw[m] = t;
        }
        rs += __shfl_xor(rs, 16);
        rs += __shfl_xor(rs, 32);
        lrow0 += rs;
        const int prow = l15;
#pragma unroll
        for (int m=0;m<4;m++)
          *reinterpret_cast<ux2*>((char*)&Ps[w][0] + prow*128 + ((m*32 + g*8) ^ ((prow&7)<<4))) = pw[m];
      }
      // ---- softmax qc=1 ----
      {
        const int lim = q1 + l15 - kv0 - g*4;
#pragma unroll
        for (int m=0;m<4;m++)
#pragma unroll
          for (int j=0;j<4;j++)
            s1[m][j] = (m*16 + j > lim) ? -1e30f : s1[m][j]*C2;
        float a0 = fmaxf(fmaxf(s1[0][0],s1[0][1]), fmaxf(s1[0][2],s1[0][3]));
        float a1 = fmaxf(fmaxf(s1[1][0],s1[1][1]), fmaxf(s1[1][2],s1[1][3]));
        float a2 = fmaxf(fmaxf(s1[2][0],s1[2][1]), fmaxf(s1[2][2],s1[2][3]));
        float a3 = fmaxf(fmaxf(s1[3][0],s1[3][1]), fmaxf(s1[3][2],s1[3][3]));
        float mx = fmaxf(fmaxf(a0,a1), fmaxf(a2,a3));
        mx = fmaxf(mx, __shfl_xor(mx, 16));
        mx = fmaxf(mx, __shfl_xor(mx, 32));
        if (__any(mx > mrow1 + 8.f)){
          float mnew = fmaxf(mrow1, mx);
          float sc = exp2f(mrow1 - mnew);
          mrow1 = mnew;
          lrow1 *= sc;
          float sct[4];
#pragma unroll
          for (int j=0;j<4;j++) sct[j] = __shfl(sc, g*4 + j);
#pragma unroll
          for (int f=0;f<8;f++)
#pragma unroll
            for (int j=0;j<4;j++) acc1[f][j] *= sct[j];
        }
        float rs = 0.f;
        ux2 pw[4];
#pragma unroll
        for (int m=0;m<4;m++){
          float p0 = exp2f(s1[m][0]-mrow1), p1 = exp2f(s1[m][1]-mrow1);
          float p2 = exp2f(s1[m][2]-mrow1), p3 = exp2f(s1[m][3]-mrow1);
          rs += (p0+p1)+(p2+p3);
          ux2 t; t[0] = (unsigned)f2bf(p0) | ((unsigned)f2bf(p1)<<16);
          t[1] = (unsigned)f2bf(p2) | ((unsigned)f2bf(p3)<<16);
          pw[m] = t;
        }
        rs += __shfl_xor(rs, 16);
        rs += __shfl_xor(rs, 32);
        lrow1 += rs;
        const int prow = 16 + l15;
#pragma unroll
        for (int m=0;m<4;m++)
          *reinterpret_cast<ux2*>((char*)&Ps[w][0] + prow*128 + ((m*32 + g*8) ^ ((prow&7)<<4))) = pw[m];
      }
      asm volatile("s_waitcnt lgkmcnt(0)" ::: "memory");
      // ---- PV: acc[q][d] += P[q][kv] * V[kv][d] ----
#pragma unroll
      for (int t=0;t<2;t++){
        const int pr0 = l15, pr1 = 16 + l15;
        bh8 pa0 = *reinterpret_cast<const bh8*>((const char*)&Ps[w][0] + pr0*128 + ((t*64 + g*16) ^ ((pr0&7)<<4)));
        bh8 pa1 = *reinterpret_cast<const bh8*>((const char*)&Ps[w][0] + pr1*128 + ((t*64 + g*16) ^ ((pr1&7)<<4)));
#pragma unroll
        for (int f=0;f<8;f++){
          const int vr = f*16 + l15;
          bh8 vb = *reinterpret_cast<const bh8*>((const char*)Vt + vr*128 + ((t*64 + g*16) ^ ((vr&7)<<4)));
          if (c0) acc0[f] = MFMA_BF16(pa0, vb, acc0[f]);
          acc1[f] = MFMA_BF16(pa1, vb, acc1[f]);
        }
      }
    }
  }
  // ---- epilogue: normalize + write (acc rows q = qbase + g*4 + j, col d = f*16 + l15) ----
  {
    float inv[4];
#pragma unroll
    for (int j=0;j<4;j++) inv[j] = 1.f / __shfl(lrow0, g*4 + j);
#pragma unroll
    for (int f=0;f<8;f++)
#pragma unroll
      for (int j=0;j<4;j++)
        O[(tokbase + q0 + g*4 + j)*4096 + h*128 + f*16 + l15] = f2bf(acc0[f][j]*inv[j]);
  }
  {
    float inv[4];
#pragma unroll
    for (int j=0;j<4;j++) inv[j] = 1.f / __shfl(lrow1, g*4 + j);
#pragma unroll
    for (int f=0;f<8;f++)
#pragma unroll
      for (int j=0;j<4;j++)
        O[(tokbase + q1 + g*4 + j)*4096 + h*128 + f*16 + l15] = f2bf(acc1[f][j]*inv[j]);
  }
}

extern "C" void kernel_launch(void* const* d_in, const int* in_sizes, int n_in,
                              void* d_out, int out_size, void* d_ws, size_t ws_size,
                              hipStream_t stream){
  const float* x  = (const float*)d_in[0];
  const float* Wq = (const float*)d_in[1];
  const float* Wk = (const float*)d_in[2];
  const float* Wv = (const float*)d_in[3];
  const float* Wo = (const float*)d_in[4];
  char* ws = (char*)d_ws;
  const size_t MB = (size_t)1 << 20;
  unsigned short* xb  = (unsigned short*)(ws);             // 32 MiB (reused as attn-out)
  unsigned short* Wqb = (unsigned short*)(ws + 32*MB);     // 32 MiB (reused for Wo)
  unsigned short* Wkb = (unsigned short*)(ws + 64*MB);     // 8 MiB
  unsigned short* Wvb = (unsigned short*)(ws + 72*MB);     // 8 MiB
  unsigned short* Qb  = (unsigned short*)(ws + 80*MB);     // 32 MiB
  unsigned short* Kb  = (unsigned short*)(ws + 112*MB);    // 8 MiB
  unsigned short* Vb  = (unsigned short*)(ws + 120*MB);    // 8 MiB  (total 128 MiB)

  const int NT = 2*2048;
  auto cvt = [&](const float* in, unsigned short* out, int n){
    cvt_kernel<<<dim3(n/1024), 256, 0, stream>>>(in, out, n);
  };
  cvt(x,  xb,  NT*4096);
  cvt(Wq, Wqb, 4096*4096);
  cvt(Wk, Wkb, 1024*4096);
  cvt(Wv, Wvb, 1024*4096);
  gemm_nt<<<dim3(32,32), 256, 0, stream>>>(xb, Wqb, Qb, NT, 4096, 4096, 0);
  gemm_nt<<<dim3(32, 8), 256, 0, stream>>>(xb, Wkb, Kb, NT, 1024, 4096, 0);
  gemm_nt<<<dim3(32, 8), 256, 0, stream>>>(xb, Wvb, Vb, NT, 1024, 4096, 0);
  cvt(Wo, Wqb, 4096*4096);                         // Wq slot now dead -> Wo
  attn_kernel<<<dim3(16,64), 256, 0, stream>>>(Qb, Kb, Vb, xb);  // x slot now dead -> attn out
  gemm_nt<<<dim3(32,32), 256, 0, stream>>>(xb, Wqb, d_out, NT, 4096, 4096, 1);
}

// Round 4
// 2087.678 us; speedup vs baseline: 3.6187x; 3.6187x over previous
//
#include <hip/hip_runtime.h>
#include <hip/hip_bf16.h>

typedef __attribute__((ext_vector_type(8))) short bh8;
typedef __attribute__((ext_vector_type(4))) float fx4;
typedef __attribute__((ext_vector_type(4))) int ix4;
typedef __attribute__((ext_vector_type(2))) unsigned int ux2;

#define MFMA_BF16(a,b,c) __builtin_amdgcn_mfma_f32_16x16x32_bf16((a),(b),(c),0,0,0)

__device__ __forceinline__ unsigned short f2bf(float f){
  union { float f; unsigned u; } x; x.f = f;
  return (unsigned short)((x.u + 0x7fffu + ((x.u >> 16) & 1u)) >> 16);
}

__device__ __forceinline__ void gl_lds16(const void* g, void* l){
  typedef const void __attribute__((address_space(1)))* gp_t;
  typedef void __attribute__((address_space(3)))* lp_t;
  __builtin_amdgcn_global_load_lds((gp_t)g, (lp_t)l, 16, 0, 0);
}

// ---------------- f32 -> bf16 (RNE), 4 elems/thread ----------------
__global__ __launch_bounds__(256) void cvt_kernel(const float* __restrict__ in,
                                                  unsigned short* __restrict__ out, int n){
  int i = (blockIdx.x * 256 + threadIdx.x) * 4;
  if (i >= n) return;
  float4 v = *reinterpret_cast<const float4*>(in + i);
  ushort4 o;
  o.x = f2bf(v.x); o.y = f2bf(v.y); o.z = f2bf(v.z); o.w = f2bf(v.w);
  *reinterpret_cast<ushort4*>(out + i) = o;
}

// ---------------- NT GEMM: C[M][N] = A[M][K] * B[N][K]^T (m97 structure) ----------------
__global__ __launch_bounds__(256) void gemm_nt(const unsigned short* __restrict__ A,
                                               const unsigned short* __restrict__ B,
                                               void* __restrict__ Cout,
                                               int M, int N, int K, int out_f32){
  __shared__ __attribute__((aligned(16))) unsigned short As[128*32];
  __shared__ __attribute__((aligned(16))) unsigned short Bs[128*32];
  const int tid = threadIdx.x, lane = tid & 63, w = tid >> 6;
  const int row0 = blockIdx.x * 128, col0 = blockIdx.y * 128;
  const int wr = w >> 1, wc = w & 1;
  fx4 acc[4][4];
#pragma unroll
  for (int m=0;m<4;m++)
#pragma unroll
    for (int n=0;n<4;n++) acc[m][n] = (fx4){0.f,0.f,0.f,0.f};

  const int ldr = lane & 15;
  const int kb  = (lane >> 4) * 16;

  for (int k0 = 0; k0 < K; k0 += 32){
    __syncthreads();
#pragma unroll
    for (int i=0;i<2;i++){
      int chunk = w*2 + i;
      int r  = chunk*16 + (lane >> 2);
      int cb = (lane & 3) * 16;
      gl_lds16((const char*)A + ((size_t)(row0 + r)*K + k0)*2 + cb, (char*)As + chunk*1024);
      gl_lds16((const char*)B + ((size_t)(col0 + r)*K + k0)*2 + cb, (char*)Bs + chunk*1024);
    }
    __syncthreads();
    bh8 af[4], bf[4];
#pragma unroll
    for (int m=0;m<4;m++)
      af[m] = *reinterpret_cast<const bh8*>((const char*)As + (wr*64 + m*16 + ldr)*64 + kb);
#pragma unroll
    for (int n=0;n<4;n++)
      bf[n] = *reinterpret_cast<const bh8*>((const char*)Bs + (wc*64 + n*16 + ldr)*64 + kb);
#pragma unroll
    for (int m=0;m<4;m++)
#pragma unroll
      for (int n=0;n<4;n++)
        acc[m][n] = MFMA_BF16(af[m], bf[n], acc[m][n]);
  }
  const int er = (lane >> 4) * 4;
  const int ec = lane & 15;
  if (out_f32){
    float* C = (float*)Cout;
#pragma unroll
    for (int m=0;m<4;m++)
#pragma unroll
      for (int n=0;n<4;n++)
#pragma unroll
        for (int j=0;j<4;j++)
          C[(size_t)(row0 + wr*64 + m*16 + er + j)*N + (col0 + wc*64 + n*16 + ec)] = acc[m][n][j];
  } else {
    unsigned short* C = (unsigned short*)Cout;
#pragma unroll
    for (int m=0;m<4;m++)
#pragma unroll
      for (int n=0;n<4;n++)
#pragma unroll
        for (int j=0;j<4;j++)
          C[(size_t)(row0 + wr*64 + m*16 + er + j)*N + (col0 + wc*64 + n*16 + ec)] = f2bf(acc[m][n][j]);
  }
}

// ---------------- causal GQA flash attention, swapped-QK in-register softmax ----------------
// 4 waves/block; wave w owns q rows {bq*128+w*16+l15} (qc=0) and {+64} (qc=1); KVBLK=64.
// S^T = mfma(K, Q): lane holds 16 P values for q=lane&15 -> in-lane softmax (2 shfl per reduce).
// K/Vt/Ps all XOR-swizzled (byte ^= (row&7)<<4) to kill bank conflicts.
// NOTE: no min-waves launch bound — round-3's (256,2) capped VGPR at 128 and
// spilled ~8.6GB/dispatch to scratch (15x regression). Live set needs ~170 VGPR.
__global__ __launch_bounds__(256) void attn_kernel(const unsigned short* __restrict__ Q,
                                                   const unsigned short* __restrict__ Km,
                                                   const unsigned short* __restrict__ Vm,
                                                   unsigned short* __restrict__ O){
  __shared__ __attribute__((aligned(16))) unsigned short Ks[64*128];   // [kv][d], 256B rows, swz
  __shared__ __attribute__((aligned(16))) unsigned short Vt[128*64];   // [d][kv], 128B rows, swz
  __shared__ __attribute__((aligned(16))) unsigned short Ps[4][32*64]; // per-wave P [q][kv], swz
  const int tid = threadIdx.x, lane = tid & 63, w = tid >> 6;
  const int g = lane >> 4, l15 = lane & 15;
  const int bq = (int)gridDim.x - 1 - (int)blockIdx.x;  // heavy blocks first
  const int head = blockIdx.y;
  const int b = head >> 5, h = head & 31, kvh = h >> 2;
  const int q0 = bq*128 + w*16;        // qc=0 base
  const int q1 = q0 + 64;              // qc=1 base
  const size_t tokbase = (size_t)b * 2048;
  const float C2 = 0.12751741104447086f;  // (1/sqrt(128)) * log2(e)

  bh8 qf0[4], qf1[4];
  {
    const char* qp0 = (const char*)Q + ((tokbase + q0 + l15)*4096 + h*128)*2;
    const char* qp1 = (const char*)Q + ((tokbase + q1 + l15)*4096 + h*128)*2;
#pragma unroll
    for (int kk=0;kk<4;kk++){
      qf0[kk] = *reinterpret_cast<const bh8*>(qp0 + kk*64 + g*16);
      qf1[kk] = *reinterpret_cast<const bh8*>(qp1 + kk*64 + g*16);
    }
  }
  float mrow0 = -1e38f, mrow1 = -1e38f, lrow0 = 0.f, lrow1 = 0.f;
  fx4 acc0[8], acc1[8];
#pragma unroll
  for (int f=0;f<8;f++){ acc0[f] = (fx4){0,0,0,0}; acc1[f] = (fx4){0,0,0,0}; }

  const int ntile = 2*bq + 2;
  for (int kt=0; kt<ntile; ++kt){
    const int kv0 = kt*64;
    __syncthreads();
    { // stage K: 64 rows x 256B, 4 x 16B per thread, swizzled
#pragma unroll
      for (int i=0;i<4;i++){
        int idx = i*256 + tid;
        int r = idx >> 4, cb = (idx & 15)*16;
        ix4 kvv = *reinterpret_cast<const ix4*>((const char*)Km + ((tokbase + kv0 + r)*1024 + kvh*128)*2 + cb);
        *reinterpret_cast<ix4*>((char*)Ks + r*256 + (cb ^ ((r&7)<<4))) = kvv;
      }
    }
    { // stage V^T: thread owns d=tid&127, kv-half kh (32 kv); swizzled 128B rows
      int d = tid & 127, kh = tid >> 7;
      const unsigned short* vsrc = Vm + (tokbase + kv0 + kh*32)*1024 + kvh*128 + d;
#pragma unroll
      for (int half=0; half<2; ++half){
        unsigned int pk[8];
#pragma unroll
        for (int e=0;e<8;e++){
          unsigned int lo = vsrc[(size_t)(half*16 + 2*e)*1024];
          unsigned int hi = vsrc[(size_t)(half*16 + 2*e+1)*1024];
          pk[e] = lo | (hi << 16);
        }
#pragma unroll
        for (int c=0;c<2;c++){
          ix4 vv; vv[0]=(int)pk[4*c]; vv[1]=(int)pk[4*c+1]; vv[2]=(int)pk[4*c+2]; vv[3]=(int)pk[4*c+3];
          *reinterpret_cast<ix4*>((char*)Vt + d*128 + ((kh*64 + half*32 + c*16) ^ ((d&7)<<4))) = vv;
        }
      }
    }
    __syncthreads();
    const bool c1 = (kv0 <= q1 + 15);   // wave-uniform
    const bool c0 = (kv0 <= q0 + 15);
    if (c1){
      fx4 s0[4], s1[4];
#pragma unroll
      for (int m=0;m<4;m++){ s0[m] = (fx4){0,0,0,0}; s1[m] = (fx4){0,0,0,0}; }
#pragma unroll
      for (int m=0;m<4;m++){
        bh8 kf[4];
        const int kr = m*16 + l15;
#pragma unroll
        for (int kk=0;kk<4;kk++)
          kf[kk] = *reinterpret_cast<const bh8*>((const char*)Ks + kr*256 + ((kk*64 + g*16) ^ ((kr&7)<<4)));
        if (c0){
#pragma unroll
          for (int kk=0;kk<4;kk++) s0[m] = MFMA_BF16(kf[kk], qf0[kk], s0[m]);
        }
#pragma unroll
        for (int kk=0;kk<4;kk++) s1[m] = MFMA_BF16(kf[kk], qf1[kk], s1[m]);
      }
      // ---- softmax qc=0 ----
      if (c0){
        const int lim = q0 + l15 - kv0 - g*4;
#pragma unroll
        for (int m=0;m<4;m++)
#pragma unroll
          for (int j=0;j<4;j++)
            s0[m][j] = (m*16 + j > lim) ? -1e30f : s0[m][j]*C2;
        float a0 = fmaxf(fmaxf(s0[0][0],s0[0][1]), fmaxf(s0[0][2],s0[0][3]));
        float a1 = fmaxf(fmaxf(s0[1][0],s0[1][1]), fmaxf(s0[1][2],s0[1][3]));
        float a2 = fmaxf(fmaxf(s0[2][0],s0[2][1]), fmaxf(s0[2][2],s0[2][3]));
        float a3 = fmaxf(fmaxf(s0[3][0],s0[3][1]), fmaxf(s0[3][2],s0[3][3]));
        float mx = fmaxf(fmaxf(a0,a1), fmaxf(a2,a3));
        mx = fmaxf(mx, __shfl_xor(mx, 16));
        mx = fmaxf(mx, __shfl_xor(mx, 32));
        if (__any(mx > mrow0 + 8.f)){
          float mnew = fmaxf(mrow0, mx);
          float sc = exp2f(mrow0 - mnew);
          mrow0 = mnew;
          lrow0 *= sc;
          float sct[4];
#pragma unroll
          for (int j=0;j<4;j++) sct[j] = __shfl(sc, g*4 + j);
#pragma unroll
          for (int f=0;f<8;f++)
#pragma unroll
            for (int j=0;j<4;j++) acc0[f][j] *= sct[j];
        }
        float rs = 0.f;
        ux2 pw[4];
#pragma unroll
        for (int m=0;m<4;m++){
          float p0 = exp2f(s0[m][0]-mrow0), p1 = exp2f(s0[m][1]-mrow0);
          float p2 = exp2f(s0[m][2]-mrow0), p3 = exp2f(s0[m][3]-mrow0);
          rs += (p0+p1)+(p2+p3);
          ux2 t; t[0] = (unsigned)f2bf(p0) | ((unsigned)f2bf(p1)<<16);
          t[1] = (unsigned)f2bf(p2) | ((unsigned)f2bf(p3)<<16);
          pw[m] = t;
        }
        rs += __shfl_xor(rs, 16);
        rs += __shfl_xor(rs, 32);
        lrow0 += rs;
        const int prow = l15;
#pragma unroll
        for (int m=0;m<4;m++)
          *reinterpret_cast<ux2*>((char*)&Ps[w][0] + prow*128 + ((m*32 + g*8) ^ ((prow&7)<<4))) = pw[m];
      }
      // ---- softmax qc=1 ----
      {
        const int lim = q1 + l15 - kv0 - g*4;
#pragma unroll
        for (int m=0;m<4;m++)
#pragma unroll
          for (int j=0;j<4;j++)
            s1[m][j] = (m*16 + j > lim) ? -1e30f : s1[m][j]*C2;
        float a0 = fmaxf(fmaxf(s1[0][0],s1[0][1]), fmaxf(s1[0][2],s1[0][3]));
        float a1 = fmaxf(fmaxf(s1[1][0],s1[1][1]), fmaxf(s1[1][2],s1[1][3]));
        float a2 = fmaxf(fmaxf(s1[2][0],s1[2][1]), fmaxf(s1[2][2],s1[2][3]));
        float a3 = fmaxf(fmaxf(s1[3][0],s1[3][1]), fmaxf(s1[3][2],s1[3][3]));
        float mx = fmaxf(fmaxf(a0,a1), fmaxf(a2,a3));
        mx = fmaxf(mx, __shfl_xor(mx, 16));
        mx = fmaxf(mx, __shfl_xor(mx, 32));
        if (__any(mx > mrow1 + 8.f)){
          float mnew = fmaxf(mrow1, mx);
          float sc = exp2f(mrow1 - mnew);
          mrow1 = mnew;
          lrow1 *= sc;
          float sct[4];
#pragma unroll
          for (int j=0;j<4;j++) sct[j] = __shfl(sc, g*4 + j);
#pragma unroll
          for (int f=0;f<8;f++)
#pragma unroll
            for (int j=0;j<4;j++) acc1[f][j] *= sct[j];
        }
        float rs = 0.f;
        ux2 pw[4];
#pragma unroll
        for (int m=0;m<4;m++){
          float p0 = exp2f(s1[m][0]-mrow1), p1 = exp2f(s1[m][1]-mrow1);
          float p2 = exp2f(s1[m][2]-mrow1), p3 = exp2f(s1[m][3]-mrow1);
          rs += (p0+p1)+(p2+p3);
          ux2 t; t[0] = (unsigned)f2bf(p0) | ((unsigned)f2bf(p1)<<16);
          t[1] = (unsigned)f2bf(p2) | ((unsigned)f2bf(p3)<<16);
          pw[m] = t;
        }
        rs += __shfl_xor(rs, 16);
        rs += __shfl_xor(rs, 32);
        lrow1 += rs;
        const int prow = 16 + l15;
#pragma unroll
        for (int m=0;m<4;m++)
          *reinterpret_cast<ux2*>((char*)&Ps[w][0] + prow*128 + ((m*32 + g*8) ^ ((prow&7)<<4))) = pw[m];
      }
      asm volatile("s_waitcnt lgkmcnt(0)" ::: "memory");
      // ---- PV: acc[q][d] += P[q][kv] * V[kv][d] ----
#pragma unroll
      for (int t=0;t<2;t++){
        const int pr0 = l15, pr1 = 16 + l15;
        bh8 pa0 = *reinterpret_cast<const bh8*>((const char*)&Ps[w][0] + pr0*128 + ((t*64 + g*16) ^ ((pr0&7)<<4)));
        bh8 pa1 = *reinterpret_cast<const bh8*>((const char*)&Ps[w][0] + pr1*128 + ((t*64 + g*16) ^ ((pr1&7)<<4)));
#pragma unroll
        for (int f=0;f<8;f++){
          const int vr = f*16 + l15;
          bh8 vb = *reinterpret_cast<const bh8*>((const char*)Vt + vr*128 + ((t*64 + g*16) ^ ((vr&7)<<4)));
          if (c0) acc0[f] = MFMA_BF16(pa0, vb, acc0[f]);
          acc1[f] = MFMA_BF16(pa1, vb, acc1[f]);
        }
      }
    }
  }
  // ---- epilogue: normalize + write (acc rows q = qbase + g*4 + j, col d = f*16 + l15) ----
  {
    float inv[4];
#pragma unroll
    for (int j=0;j<4;j++) inv[j] = 1.f / __shfl(lrow0, g*4 + j);
#pragma unroll
    for (int f=0;f<8;f++)
#pragma unroll
      for (int j=0;j<4;j++)
        O[(tokbase + q0 + g*4 + j)*4096 + h*128 + f*16 + l15] = f2bf(acc0[f][j]*inv[j]);
  }
  {
    float inv[4];
#pragma unroll
    for (int j=0;j<4;j++) inv[j] = 1.f / __shfl(lrow1, g*4 + j);
#pragma unroll
    for (int f=0;f<8;f++)
#pragma unroll
      for (int j=0;j<4;j++)
        O[(tokbase + q1 + g*4 + j)*4096 + h*128 + f*16 + l15] = f2bf(acc1[f][j]*inv[j]);
  }
}

extern "C" void kernel_launch(void* const* d_in, const int* in_sizes, int n_in,
                              void* d_out, int out_size, void* d_ws, size_t ws_size,
                              hipStream_t stream){
  const float* x  = (const float*)d_in[0];
  const float* Wq = (const float*)d_in[1];
  const float* Wk = (const float*)d_in[2];
  const float* Wv = (const float*)d_in[3];
  const float* Wo = (const float*)d_in[4];
  char* ws = (char*)d_ws;
  const size_t MB = (size_t)1 << 20;
  unsigned short* xb  = (unsigned short*)(ws);             // 32 MiB (reused as attn-out)
  unsigned short* Wqb = (unsigned short*)(ws + 32*MB);     // 32 MiB (reused for Wo)
  unsigned short* Wkb = (unsigned short*)(ws + 64*MB);     // 8 MiB
  unsigned short* Wvb = (unsigned short*)(ws + 72*MB);     // 8 MiB
  unsigned short* Qb  = (unsigned short*)(ws + 80*MB);     // 32 MiB
  unsigned short* Kb  = (unsigned short*)(ws + 112*MB);    // 8 MiB
  unsigned short* Vb  = (unsigned short*)(ws + 120*MB);    // 8 MiB  (total 128 MiB)

  const int NT = 2*2048;
  auto cvt = [&](const float* in, unsigned short* out, int n){
    cvt_kernel<<<dim3(n/1024), 256, 0, stream>>>(in, out, n);
  };
  cvt(x,  xb,  NT*4096);
  cvt(Wq, Wqb, 4096*4096);
  cvt(Wk, Wkb, 1024*4096);
  cvt(Wv, Wvb, 1024*4096);
  gemm_nt<<<dim3(32,32), 256, 0, stream>>>(xb, Wqb, Qb, NT, 4096, 4096, 0);
  gemm_nt<<<dim3(32, 8), 256, 0, stream>>>(xb, Wkb, Kb, NT, 1024, 4096, 0);
  gemm_nt<<<dim3(32, 8), 256, 0, stream>>>(xb, Wvb, Vb, NT, 1024, 4096, 0);
  cvt(Wo, Wqb, 4096*4096);                         // Wq slot now dead -> Wo
  attn_kernel<<<dim3(16,64), 256, 0, stream>>>(Qb, Kb, Vb, xb);  // x slot now dead -> attn out
  gemm_nt<<<dim3(32,32), 256, 0, stream>>>(xb, Wqb, d_out, NT, 4096, 4096, 1);
}

// Round 6
// 1089.842 us; speedup vs baseline: 6.9318x; 1.9156x over previous
//
#include <hip/hip_runtime.h>
#include <hip/hip_bf16.h>

typedef __attribute__((ext_vector_type(8))) short bh8;
typedef __attribute__((ext_vector_type(4))) float fx4;
typedef __attribute__((ext_vector_type(4))) int ix4;
typedef __attribute__((ext_vector_type(2))) unsigned int ux2;

#define MFMA_BF16(a,b,c) __builtin_amdgcn_mfma_f32_16x16x32_bf16((a),(b),(c),0,0,0)

__device__ __forceinline__ unsigned short f2bf(float f){
  union { float f; unsigned u; } x; x.f = f;
  return (unsigned short)((x.u + 0x7fffu + ((x.u >> 16) & 1u)) >> 16);
}

__device__ __forceinline__ void gl_lds16(const void* g, void* l){
  typedef const void __attribute__((address_space(1)))* gp_t;
  typedef void __attribute__((address_space(3)))* lp_t;
  __builtin_amdgcn_global_load_lds((gp_t)g, (lp_t)l, 16, 0, 0);
}

// ---------------- f32 -> bf16 (RNE), 4 elems/thread ----------------
__global__ __launch_bounds__(256) void cvt_kernel(const float* __restrict__ in,
                                                  unsigned short* __restrict__ out, int n){
  int i = (blockIdx.x * 256 + threadIdx.x) * 4;
  if (i >= n) return;
  float4 v = *reinterpret_cast<const float4*>(in + i);
  ushort4 o;
  o.x = f2bf(v.x); o.y = f2bf(v.y); o.z = f2bf(v.z); o.w = f2bf(v.w);
  *reinterpret_cast<ushort4*>(out + i) = o;
}

// ---------------- NT GEMM: C[M][N] = A[M][K] * B[N][K]^T (m97 structure) ----------------
__global__ __launch_bounds__(256) void gemm_nt(const unsigned short* __restrict__ A,
                                               const unsigned short* __restrict__ B,
                                               void* __restrict__ Cout,
                                               int M, int N, int K, int out_f32){
  __shared__ __attribute__((aligned(16))) unsigned short As[128*32];
  __shared__ __attribute__((aligned(16))) unsigned short Bs[128*32];
  const int tid = threadIdx.x, lane = tid & 63, w = tid >> 6;
  const int row0 = blockIdx.x * 128, col0 = blockIdx.y * 128;
  const int wr = w >> 1, wc = w & 1;
  fx4 acc[4][4];
#pragma unroll
  for (int m=0;m<4;m++)
#pragma unroll
    for (int n=0;n<4;n++) acc[m][n] = (fx4){0.f,0.f,0.f,0.f};

  const int ldr = lane & 15;
  const int kb  = (lane >> 4) * 16;

  for (int k0 = 0; k0 < K; k0 += 32){
    __syncthreads();
#pragma unroll
    for (int i=0;i<2;i++){
      int chunk = w*2 + i;
      int r  = chunk*16 + (lane >> 2);
      int cb = (lane & 3) * 16;
      gl_lds16((const char*)A + ((size_t)(row0 + r)*K + k0)*2 + cb, (char*)As + chunk*1024);
      gl_lds16((const char*)B + ((size_t)(col0 + r)*K + k0)*2 + cb, (char*)Bs + chunk*1024);
    }
    __syncthreads();
    bh8 af[4], bf[4];
#pragma unroll
    for (int m=0;m<4;m++)
      af[m] = *reinterpret_cast<const bh8*>((const char*)As + (wr*64 + m*16 + ldr)*64 + kb);
#pragma unroll
    for (int n=0;n<4;n++)
      bf[n] = *reinterpret_cast<const bh8*>((const char*)Bs + (wc*64 + n*16 + ldr)*64 + kb);
#pragma unroll
    for (int m=0;m<4;m++)
#pragma unroll
      for (int n=0;n<4;n++)
        acc[m][n] = MFMA_BF16(af[m], bf[n], acc[m][n]);
  }
  const int er = (lane >> 4) * 4;
  const int ec = lane & 15;
  if (out_f32){
    float* C = (float*)Cout;
#pragma unroll
    for (int m=0;m<4;m++)
#pragma unroll
      for (int n=0;n<4;n++)
#pragma unroll
        for (int j=0;j<4;j++)
          C[(size_t)(row0 + wr*64 + m*16 + er + j)*N + (col0 + wc*64 + n*16 + ec)] = acc[m][n][j];
  } else {
    unsigned short* C = (unsigned short*)Cout;
#pragma unroll
    for (int m=0;m<4;m++)
#pragma unroll
      for (int n=0;n<4;n++)
#pragma unroll
        for (int j=0;j<4;j++)
          C[(size_t)(row0 + wr*64 + m*16 + er + j)*N + (col0 + wc*64 + n*16 + ec)] = f2bf(acc[m][n][j]);
  }
}

// ---------------- causal GQA flash attention ----------------
// 4 waves/block, wave owns 16 q rows (q0 = bq*64 + w*16); KVBLK=64; grid (32, 64).
// Swapped QK (S^T = mfma(K,Q)) -> in-lane softmax (16 scores/lane, 4 shfl total).
// K staged by global_load_lds with PRE-SWIZZLED SOURCE (linear LDS dest, zero VALU);
// V^T reg-staged; K/Vt/Ps reads swizzled byte ^= (row&7)<<4 (conflict-free).
// Register budget is the design constraint: single q-chunk keeps VGPR ~140
// (round 4's dual-chunk hit 216 -> 2 waves/SIMD -> 6% occupancy -> 3x slower).
__global__ __launch_bounds__(256) void attn_kernel(const unsigned short* __restrict__ Q,
                                                   const unsigned short* __restrict__ Km,
                                                   const unsigned short* __restrict__ Vm,
                                                   unsigned short* __restrict__ O){
  __shared__ __attribute__((aligned(16))) unsigned short Ks[64*128];   // [kv][d], 256B rows, swz content
  __shared__ __attribute__((aligned(16))) unsigned short Vt[128*64];   // [d][kv], 128B rows, swz
  __shared__ __attribute__((aligned(16))) unsigned short Ps[4][16*64]; // per-wave P[q][kv], 128B rows, swz
  const int tid = threadIdx.x, lane = tid & 63, w = tid >> 6;
  const int g = lane >> 4, l15 = lane & 15;
  const int bq = (int)gridDim.x - 1 - (int)blockIdx.x;  // heavy blocks first
  const int head = blockIdx.y;
  const int b = head >> 5, h = head & 31, kvh = h >> 2;
  const int q0 = bq*64 + w*16;
  const size_t tokbase = (size_t)b * 2048;
  const float C2 = 0.12751741104447086f;  // (1/sqrt(128)) * log2(e)

  bh8 qf[4];
  {
    const char* qp = (const char*)Q + ((tokbase + q0 + l15)*4096 + h*128)*2;
#pragma unroll
    for (int kk=0;kk<4;kk++) qf[kk] = *reinterpret_cast<const bh8*>(qp + kk*64 + g*16);
  }
  float mrow = -1e38f, lrow = 0.f;
  fx4 acc[8];
#pragma unroll
  for (int f=0;f<8;f++) acc[f] = (fx4){0,0,0,0};

  const int ntile = bq + 1;
  for (int kt=0; kt<ntile; ++kt){
    const int kv0 = kt*64;
    __syncthreads();
    // ---- stage K: gl_lds16, linear LDS dest, pre-swizzled global source ----
    // LDS chunk (r,c) holds global chunk c^(r&7); read side applies the same XOR.
#pragma unroll
    for (int i=0;i<4;i++){
      int r = i*16 + w*4 + (lane>>4);
      int c = (lane & 15) ^ (r & 7);
      gl_lds16((const char*)Km + ((tokbase + kv0 + r)*1024 + kvh*128)*2 + c*16,
               (char*)Ks + i*4096 + w*1024);
    }
    // ---- stage V^T: thread owns d=tid&127, kv-half kh (32 kv); swizzled 128B rows ----
    {
      int d = tid & 127, kh = tid >> 7;
      const unsigned short* vsrc = Vm + (tokbase + kv0 + kh*32)*1024 + kvh*128 + d;
#pragma unroll
      for (int half=0; half<2; ++half){
        unsigned int pk[8];
#pragma unroll
        for (int e=0;e<8;e++){
          unsigned int lo = vsrc[(size_t)(half*16 + 2*e)*1024];
          unsigned int hi = vsrc[(size_t)(half*16 + 2*e+1)*1024];
          pk[e] = lo | (hi << 16);
        }
#pragma unroll
        for (int c2=0;c2<2;c2++){
          ix4 vv; vv[0]=(int)pk[4*c2]; vv[1]=(int)pk[4*c2+1]; vv[2]=(int)pk[4*c2+2]; vv[3]=(int)pk[4*c2+3];
          *reinterpret_cast<ix4*>((char*)Vt + d*128 + ((kh*64 + half*32 + c2*16) ^ ((d&7)<<4))) = vv;
        }
      }
    }
    __syncthreads();
    // ---- QK^T (swapped): s[m] holds S[kv=m*16+g*4+j][q=l15] ----
    fx4 s[4];
#pragma unroll
    for (int m=0;m<4;m++) s[m] = (fx4){0,0,0,0};
#pragma unroll
    for (int m=0;m<4;m++){
      const int kr = m*16 + l15;
#pragma unroll
      for (int kk=0;kk<4;kk++){
        bh8 kf = *reinterpret_cast<const bh8*>((const char*)Ks + kr*256 + ((kk*64 + g*16) ^ ((kr&7)<<4)));
        s[m] = MFMA_BF16(kf, qf[kk], s[m]);
      }
    }
    // ---- mask + scale (log2 domain) ----
    const int lim = q0 + l15 - kv0 - g*4;
#pragma unroll
    for (int m=0;m<4;m++)
#pragma unroll
      for (int j=0;j<4;j++)
        s[m][j] = (m*16 + j > lim) ? -1e30f : s[m][j]*C2;
    // ---- in-lane max (16) + cross-g reduce (lanes l15, +16, +32, +48) ----
    float mx = fmaxf(fmaxf(fmaxf(s[0][0],s[0][1]), fmaxf(s[0][2],s[0][3])),
                     fmaxf(fmaxf(s[1][0],s[1][1]), fmaxf(s[1][2],s[1][3])));
    mx = fmaxf(mx, fmaxf(fmaxf(fmaxf(s[2][0],s[2][1]), fmaxf(s[2][2],s[2][3])),
                         fmaxf(fmaxf(s[3][0],s[3][1]), fmaxf(s[3][2],s[3][3]))));
    mx = fmaxf(mx, __shfl_xor(mx, 16));
    mx = fmaxf(mx, __shfl_xor(mx, 32));
    // ---- defer-max: rescale only when max grew by >8 (p bounded by 2^8) ----
    if (__any(mx > mrow + 8.f)){
      float mnew = fmaxf(mrow, mx);
      float sc = exp2f(mrow - mnew);
      mrow = mnew;
      lrow *= sc;
      float sct[4];
#pragma unroll
      for (int j=0;j<4;j++) sct[j] = __shfl(sc, g*4 + j);
#pragma unroll
      for (int f=0;f<8;f++)
#pragma unroll
        for (int j=0;j<4;j++) acc[f][j] *= sct[j];
    }
    // ---- exp + row-sum + pack P to bf16 ----
    float rs = 0.f;
    ux2 pw[4];
#pragma unroll
    for (int m=0;m<4;m++){
      float p0 = exp2f(s[m][0]-mrow), p1 = exp2f(s[m][1]-mrow);
      float p2 = exp2f(s[m][2]-mrow), p3 = exp2f(s[m][3]-mrow);
      rs += (p0+p1)+(p2+p3);
      ux2 t; t[0] = (unsigned)f2bf(p0) | ((unsigned)f2bf(p1)<<16);
      t[1] = (unsigned)f2bf(p2) | ((unsigned)f2bf(p3)<<16);
      pw[m] = t;
    }
    rs += __shfl_xor(rs, 16);
    rs += __shfl_xor(rs, 32);
    lrow += rs;
#pragma unroll
    for (int m=0;m<4;m++)
      *reinterpret_cast<ux2*>((char*)&Ps[w][0] + l15*128 + ((m*32 + g*8) ^ ((l15&7)<<4))) = pw[m];
    asm volatile("s_waitcnt lgkmcnt(0)" ::: "memory");
    // ---- PV: acc[q][d] += P[q][kv] * V[kv][d] ----
#pragma unroll
    for (int t=0;t<2;t++){
      bh8 pa = *reinterpret_cast<const bh8*>((const char*)&Ps[w][0] + l15*128 + ((t*64 + g*16) ^ ((l15&7)<<4)));
#pragma unroll
      for (int f=0;f<8;f++){
        const int vr = f*16 + l15;
        bh8 vb = *reinterpret_cast<const bh8*>((const char*)Vt + vr*128 + ((t*64 + g*16) ^ ((vr&7)<<4)));
        acc[f] = MFMA_BF16(pa, vb, acc[f]);
      }
    }
  }
  // ---- epilogue: normalize + write (row q = q0 + g*4 + j, col d = f*16 + l15) ----
  {
    float inv[4];
#pragma unroll
    for (int j=0;j<4;j++) inv[j] = 1.f / __shfl(lrow, g*4 + j);
#pragma unroll
    for (int f=0;f<8;f++)
#pragma unroll
      for (int j=0;j<4;j++)
        O[(tokbase + q0 + g*4 + j)*4096 + h*128 + f*16 + l15] = f2bf(acc[f][j]*inv[j]);
  }
}

extern "C" void kernel_launch(void* const* d_in, const int* in_sizes, int n_in,
                              void* d_out, int out_size, void* d_ws, size_t ws_size,
                              hipStream_t stream){
  const float* x  = (const float*)d_in[0];
  const float* Wq = (const float*)d_in[1];
  const float* Wk = (const float*)d_in[2];
  const float* Wv = (const float*)d_in[3];
  const float* Wo = (const float*)d_in[4];
  char* ws = (char*)d_ws;
  const size_t MB = (size_t)1 << 20;
  unsigned short* xb  = (unsigned short*)(ws);             // 32 MiB (reused as attn-out)
  unsigned short* Wqb = (unsigned short*)(ws + 32*MB);     // 32 MiB (reused for Wo)
  unsigned short* Wkb = (unsigned short*)(ws + 64*MB);     // 8 MiB
  unsigned short* Wvb = (unsigned short*)(ws + 72*MB);     // 8 MiB
  unsigned short* Qb  = (unsigned short*)(ws + 80*MB);     // 32 MiB
  unsigned short* Kb  = (unsigned short*)(ws + 112*MB);    // 8 MiB
  unsigned short* Vb  = (unsigned short*)(ws + 120*MB);    // 8 MiB  (total 128 MiB)

  const int NT = 2*2048;
  auto cvt = [&](const float* in, unsigned short* out, int n){
    cvt_kernel<<<dim3(n/1024), 256, 0, stream>>>(in, out, n);
  };
  cvt(x,  xb,  NT*4096);
  cvt(Wq, Wqb, 4096*4096);
  cvt(Wk, Wkb, 1024*4096);
  cvt(Wv, Wvb, 1024*4096);
  gemm_nt<<<dim3(32,32), 256, 0, stream>>>(xb, Wqb, Qb, NT, 4096, 4096, 0);
  gemm_nt<<<dim3(32, 8), 256, 0, stream>>>(xb, Wkb, Kb, NT, 1024, 4096, 0);
  gemm_nt<<<dim3(32, 8), 256, 0, stream>>>(xb, Wvb, Vb, NT, 1024, 4096, 0);
  cvt(Wo, Wqb, 4096*4096);                         // Wq slot now dead -> Wo
  attn_kernel<<<dim3(32,64), 256, 0, stream>>>(Qb, Kb, Vb, xb);  // x slot now dead -> attn out
  gemm_nt<<<dim3(32,32), 256, 0, stream>>>(xb, Wqb, d_out, NT, 4096, 4096, 1);
}

// Round 8
// 1073.122 us; speedup vs baseline: 7.0398x; 1.0156x over previous
//
#include <hip/hip_runtime.h>
#include <hip/hip_bf16.h>

typedef __attribute__((ext_vector_type(8))) short bh8;
typedef __attribute__((ext_vector_type(4))) float fx4;
typedef __attribute__((ext_vector_type(4))) int ix4;
typedef __attribute__((ext_vector_type(2))) unsigned int ux2;

#define MFMA_BF16(a,b,c) __builtin_amdgcn_mfma_f32_16x16x32_bf16((a),(b),(c),0,0,0)

__device__ __forceinline__ unsigned short f2bf(float f){
  union { float f; unsigned u; } x; x.f = f;
  return (unsigned short)((x.u + 0x7fffu + ((x.u >> 16) & 1u)) >> 16);
}

__device__ __forceinline__ void gl_lds16(const void* g, void* l){
  typedef const void __attribute__((address_space(1)))* gp_t;
  typedef void __attribute__((address_space(3)))* lp_t;
  __builtin_amdgcn_global_load_lds((gp_t)g, (lp_t)l, 16, 0, 0);
}

// ---------------- f32 -> bf16 (RNE), 4 elems/thread ----------------
__global__ __launch_bounds__(256) void cvt_kernel(const float* __restrict__ in,
                                                  unsigned short* __restrict__ out, int n){
  int i = (blockIdx.x * 256 + threadIdx.x) * 4;
  if (i >= n) return;
  float4 v = *reinterpret_cast<const float4*>(in + i);
  ushort4 o;
  o.x = f2bf(v.x); o.y = f2bf(v.y); o.z = f2bf(v.z); o.w = f2bf(v.w);
  *reinterpret_cast<ushort4*>(out + i) = o;
}

// ---------------- NT GEMM: C[M][N] = A[M][K] * B[N][K]^T (m97 structure) ----------------
// 1-D grid with bijective XCD swizzle (nwg % 8 == 0 for all our launches):
// blocks on one XCD get consecutive swz ids -> same A-panel, B-panels L2-resident.
__global__ __launch_bounds__(256) void gemm_nt(const unsigned short* __restrict__ A,
                                               const unsigned short* __restrict__ B,
                                               void* __restrict__ Cout,
                                               int M, int N, int K, int out_f32){
  __shared__ __attribute__((aligned(16))) unsigned short As[128*32];
  __shared__ __attribute__((aligned(16))) unsigned short Bs[128*32];
  const int tid = threadIdx.x, lane = tid & 63, w = tid >> 6;
  const int nby = N >> 7;
  const int nwg = (int)gridDim.x;
  const int id  = (int)blockIdx.x;
  const int swz = (id & 7) * (nwg >> 3) + (id >> 3);   // XCD-aware remap
  const int bx  = swz / nby, by = swz - bx*nby;
  const int row0 = bx * 128, col0 = by * 128;
  const int wr = w >> 1, wc = w & 1;
  fx4 acc[4][4];
#pragma unroll
  for (int m=0;m<4;m++)
#pragma unroll
    for (int n=0;n<4;n++) acc[m][n] = (fx4){0.f,0.f,0.f,0.f};

  const int ldr = lane & 15;
  const int kb  = (lane >> 4) * 16;

  for (int k0 = 0; k0 < K; k0 += 32){
    __syncthreads();
#pragma unroll
    for (int i=0;i<2;i++){
      int chunk = w*2 + i;
      int r  = chunk*16 + (lane >> 2);
      int cb = (lane & 3) * 16;
      gl_lds16((const char*)A + ((size_t)(row0 + r)*K + k0)*2 + cb, (char*)As + chunk*1024);
      gl_lds16((const char*)B + ((size_t)(col0 + r)*K + k0)*2 + cb, (char*)Bs + chunk*1024);
    }
    __syncthreads();
    bh8 af[4], bf[4];
#pragma unroll
    for (int m=0;m<4;m++)
      af[m] = *reinterpret_cast<const bh8*>((const char*)As + (wr*64 + m*16 + ldr)*64 + kb);
#pragma unroll
    for (int n=0;n<4;n++)
      bf[n] = *reinterpret_cast<const bh8*>((const char*)Bs + (wc*64 + n*16 + ldr)*64 + kb);
#pragma unroll
    for (int m=0;m<4;m++)
#pragma unroll
      for (int n=0;n<4;n++)
        acc[m][n] = MFMA_BF16(af[m], bf[n], acc[m][n]);
  }
  const int er = (lane >> 4) * 4;
  const int ec = lane & 15;
  if (out_f32){
    float* C = (float*)Cout;
#pragma unroll
    for (int m=0;m<4;m++)
#pragma unroll
      for (int n=0;n<4;n++)
#pragma unroll
        for (int j=0;j<4;j++)
          C[(size_t)(row0 + wr*64 + m*16 + er + j)*N + (col0 + wc*64 + n*16 + ec)] = acc[m][n][j];
  } else {
    unsigned short* C = (unsigned short*)Cout;
#pragma unroll
    for (int m=0;m<4;m++)
#pragma unroll
      for (int n=0;n<4;n++)
#pragma unroll
        for (int j=0;j<4;j++)
          C[(size_t)(row0 + wr*64 + m*16 + er + j)*N + (col0 + wc*64 + n*16 + ec)] = f2bf(acc[m][n][j]);
  }
}

// ---------------- causal GQA flash attention ----------------
// 4 waves/block, wave owns 16 q rows (q0 = bq*64 + w*16); KVBLK=64; grid (32, 64).
// Q/K/V read from the PACKED QKV buffer, row stride QKS=6144 (Q cols 0-4095,
// K 4096-5119, V 5120-6143; pointers pre-offset). O written at stride 4096.
// Swapped QK (S^T = mfma(K,Q)) -> in-lane softmax; K staged by global_load_lds
// with pre-swizzled source; V^T reg-staged; reads swizzled byte ^= (row&7)<<4.
// No min-waves bound: VGPR must float (~84) or it spills (round-3 lesson).
__global__ __launch_bounds__(256) void attn_kernel(const unsigned short* __restrict__ Q,
                                                   const unsigned short* __restrict__ Km,
                                                   const unsigned short* __restrict__ Vm,
                                                   unsigned short* __restrict__ O){
  const int QKS = 6144;
  __shared__ __attribute__((aligned(16))) unsigned short Ks[64*128];   // [kv][d], 256B rows, swz content
  __shared__ __attribute__((aligned(16))) unsigned short Vt[128*64];   // [d][kv], 128B rows, swz
  __shared__ __attribute__((aligned(16))) unsigned short Ps[4][16*64]; // per-wave P[q][kv], 128B rows, swz
  const int tid = threadIdx.x, lane = tid & 63, w = tid >> 6;
  const int g = lane >> 4, l15 = lane & 15;
  const int bq = (int)gridDim.x - 1 - (int)blockIdx.x;  // heavy blocks first
  const int head = blockIdx.y;
  const int b = head >> 5, h = head & 31, kvh = h >> 2;
  const int q0 = bq*64 + w*16;
  const size_t tokbase = (size_t)b * 2048;
  const float C2 = 0.12751741104447086f;  // (1/sqrt(128)) * log2(e)

  bh8 qf[4];
  {
    const char* qp = (const char*)Q + ((tokbase + q0 + l15)*QKS + h*128)*2;
#pragma unroll
    for (int kk=0;kk<4;kk++) qf[kk] = *reinterpret_cast<const bh8*>(qp + kk*64 + g*16);
  }
  float mrow = -1e38f, lrow = 0.f;
  fx4 acc[8];
#pragma unroll
  for (int f=0;f<8;f++) acc[f] = (fx4){0,0,0,0};

  const int ntile = bq + 1;
  for (int kt=0; kt<ntile; ++kt){
    const int kv0 = kt*64;
    __syncthreads();
    // ---- stage K: gl_lds16, linear LDS dest, pre-swizzled global source ----
#pragma unroll
    for (int i=0;i<4;i++){
      int r = i*16 + w*4 + (lane>>4);
      int c = (lane & 15) ^ (r & 7);
      gl_lds16((const char*)Km + ((tokbase + kv0 + r)*QKS + kvh*128)*2 + c*16,
               (char*)Ks + i*4096 + w*1024);
    }
    // ---- stage V^T: thread owns d=tid&127, kv-half kh (32 kv); swizzled 128B rows ----
    {
      int d = tid & 127, kh = tid >> 7;
      const unsigned short* vsrc = Vm + (tokbase + kv0 + kh*32)*QKS + kvh*128 + d;
#pragma unroll
      for (int half=0; half<2; ++half){
        unsigned int pk[8];
#pragma unroll
        for (int e=0;e<8;e++){
          unsigned int lo = vsrc[(size_t)(half*16 + 2*e)*QKS];
          unsigned int hi = vsrc[(size_t)(half*16 + 2*e+1)*QKS];
          pk[e] = lo | (hi << 16);
        }
#pragma unroll
        for (int c2=0;c2<2;c2++){
          ix4 vv; vv[0]=(int)pk[4*c2]; vv[1]=(int)pk[4*c2+1]; vv[2]=(int)pk[4*c2+2]; vv[3]=(int)pk[4*c2+3];
          *reinterpret_cast<ix4*>((char*)Vt + d*128 + ((kh*64 + half*32 + c2*16) ^ ((d&7)<<4))) = vv;
        }
      }
    }
    __syncthreads();
    // ---- QK^T (swapped): s[m] holds S[kv=m*16+g*4+j][q=l15] ----
    fx4 s[4];
#pragma unroll
    for (int m=0;m<4;m++) s[m] = (fx4){0,0,0,0};
#pragma unroll
    for (int m=0;m<4;m++){
      const int kr = m*16 + l15;
#pragma unroll
      for (int kk=0;kk<4;kk++){
        bh8 kf = *reinterpret_cast<const bh8*>((const char*)Ks + kr*256 + ((kk*64 + g*16) ^ ((kr&7)<<4)));
        s[m] = MFMA_BF16(kf, qf[kk], s[m]);
      }
    }
    // ---- mask + scale (log2 domain) ----
    const int lim = q0 + l15 - kv0 - g*4;
#pragma unroll
    for (int m=0;m<4;m++)
#pragma unroll
      for (int j=0;j<4;j++)
        s[m][j] = (m*16 + j > lim) ? -1e30f : s[m][j]*C2;
    // ---- in-lane max (16) + cross-g reduce ----
    float mx = fmaxf(fmaxf(fmaxf(s[0][0],s[0][1]), fmaxf(s[0][2],s[0][3])),
                     fmaxf(fmaxf(s[1][0],s[1][1]), fmaxf(s[1][2],s[1][3])));
    mx = fmaxf(mx, fmaxf(fmaxf(fmaxf(s[2][0],s[2][1]), fmaxf(s[2][2],s[2][3])),
                         fmaxf(fmaxf(s[3][0],s[3][1]), fmaxf(s[3][2],s[3][3]))));
    mx = fmaxf(mx, __shfl_xor(mx, 16));
    mx = fmaxf(mx, __shfl_xor(mx, 32));
    // ---- defer-max: rescale only when max grew by >8 ----
    if (__any(mx > mrow + 8.f)){
      float mnew = fmaxf(mrow, mx);
      float sc = exp2f(mrow - mnew);
      mrow = mnew;
      lrow *= sc;
      float sct[4];
#pragma unroll
      for (int j=0;j<4;j++) sct[j] = __shfl(sc, g*4 + j);
#pragma unroll
      for (int f=0;f<8;f++)
#pragma unroll
        for (int j=0;j<4;j++) acc[f][j] *= sct[j];
    }
    // ---- exp + row-sum + pack P to bf16 ----
    float rs = 0.f;
    ux2 pw[4];
#pragma unroll
    for (int m=0;m<4;m++){
      float p0 = exp2f(s[m][0]-mrow), p1 = exp2f(s[m][1]-mrow);
      float p2 = exp2f(s[m][2]-mrow), p3 = exp2f(s[m][3]-mrow);
      rs += (p0+p1)+(p2+p3);
      ux2 t; t[0] = (unsigned)f2bf(p0) | ((unsigned)f2bf(p1)<<16);
      t[1] = (unsigned)f2bf(p2) | ((unsigned)f2bf(p3)<<16);
      pw[m] = t;
    }
    rs += __shfl_xor(rs, 16);
    rs += __shfl_xor(rs, 32);
    lrow += rs;
#pragma unroll
    for (int m=0;m<4;m++)
      *reinterpret_cast<ux2*>((char*)&Ps[w][0] + l15*128 + ((m*32 + g*8) ^ ((l15&7)<<4))) = pw[m];
    asm volatile("s_waitcnt lgkmcnt(0)" ::: "memory");
    // ---- PV: acc[q][d] += P[q][kv] * V[kv][d] ----
#pragma unroll
    for (int t=0;t<2;t++){
      bh8 pa = *reinterpret_cast<const bh8*>((const char*)&Ps[w][0] + l15*128 + ((t*64 + g*16) ^ ((l15&7)<<4)));
#pragma unroll
      for (int f=0;f<8;f++){
        const int vr = f*16 + l15;
        bh8 vb = *reinterpret_cast<const bh8*>((const char*)Vt + vr*128 + ((t*64 + g*16) ^ ((vr&7)<<4)));
        acc[f] = MFMA_BF16(pa, vb, acc[f]);
      }
    }
  }
  // ---- epilogue: normalize + write (row q = q0 + g*4 + j, col d = f*16 + l15) ----
  {
    float inv[4];
#pragma unroll
    for (int j=0;j<4;j++) inv[j] = 1.f / __shfl(lrow, g*4 + j);
#pragma unroll
    for (int f=0;f<8;f++)
#pragma unroll
      for (int j=0;j<4;j++)
        O[(tokbase + q0 + g*4 + j)*4096 + h*128 + f*16 + l15] = f2bf(acc[f][j]*inv[j]);
  }
}

extern "C" void kernel_launch(void* const* d_in, const int* in_sizes, int n_in,
                              void* d_out, int out_size, void* d_ws, size_t ws_size,
                              hipStream_t stream){
  const float* x  = (const float*)d_in[0];
  const float* Wq = (const float*)d_in[1];
  const float* Wk = (const float*)d_in[2];
  const float* Wv = (const float*)d_in[3];
  const float* Wo = (const float*)d_in[4];
  char* ws = (char*)d_ws;
  const size_t MB = (size_t)1 << 20;
  // Workspace (128 MiB total):
  //   [0,32)    xb   : x bf16 [4096][4096]; reused as attn-out
  //   [32,80)   Wb   : packed Wqkv bf16 [6144][4096]; reused for Wo after QKV GEMM
  //   [80,128)  QKVb : packed QKV bf16 [4096][6144]
  unsigned short* xb   = (unsigned short*)(ws);
  unsigned short* Wb   = (unsigned short*)(ws + 32*MB);
  unsigned short* QKVb = (unsigned short*)(ws + 80*MB);

  const int NT = 2*2048;
  auto cvt = [&](const float* in, unsigned short* out, int n){
    cvt_kernel<<<dim3(n/1024), 256, 0, stream>>>(in, out, n);
  };
  cvt(x,  xb, NT*4096);
  cvt(Wq, Wb,                     4096*4096);   // rows 0..4095
  cvt(Wk, Wb + (size_t)4096*4096, 1024*4096);   // rows 4096..5119
  cvt(Wv, Wb + (size_t)5120*4096, 1024*4096);   // rows 5120..6143
  // fused QKV projection: [4096][6144] = xb * Wb^T   (1536 blocks, 6/CU)
  gemm_nt<<<dim3(1536), 256, 0, stream>>>(xb, Wb, QKVb, NT, 6144, 4096, 0);
  cvt(Wo, Wb, 4096*4096);                       // Wb slot dead -> Wo
  attn_kernel<<<dim3(32,64), 256, 0, stream>>>(QKVb, QKVb + 4096, QKVb + 5120, xb);
  gemm_nt<<<dim3(1024), 256, 0, stream>>>(xb, Wb, d_out, NT, 4096, 4096, 1);
}